// Round 7
// baseline (782.640 us; speedup 1.0000x reference)
//
#include <hip/hip_runtime.h>
#include <hip/hip_bf16.h>
#include <type_traits>

// Problem: PredicateLevelEncoder  B=32 T=64 N=36 VD=2048 H=512 S=300 Hc=256
// Device tensors are f32; MFMA operands converted to bf16 in ws; f32 outputs.

typedef __hip_bfloat16 bf16;
typedef unsigned int uint32;
typedef unsigned short ushort_t;
typedef __attribute__((ext_vector_type(8))) short s8v;     // 8 bf16
typedef __attribute__((ext_vector_type(4))) float f4v;     // mfma accum

__device__ inline f4v mfma16(s8v a, s8v b, f4v c) {
    return __builtin_amdgcn_mfma_f32_16x16x32_bf16(a, b, c, 0, 0, 0);
}
__device__ inline float sigf(float x) {
    return __builtin_amdgcn_rcpf(1.f + __expf(-x));
}
__device__ inline float tanh_(float x) {
    return 1.f - 2.f * __builtin_amdgcn_rcpf(1.f + __expf(2.f * x));
}
__device__ inline float bf2f(ushort_t u) {
    union { uint32 i; float f; } p; p.i = (uint32)u << 16; return p.f;
}
__device__ inline ushort_t f2bf(float f) {
    return __bfloat16_as_ushort(__float2bfloat16(f));
}
__device__ inline void gload_lds16(const bf16* g, bf16* l) {
    __builtin_amdgcn_global_load_lds(
        (const __attribute__((address_space(1))) void*)g,
        (__attribute__((address_space(3))) void*)l, 16, 0, 0);
}

// ---------------------------------------------------------------------------
// Fused f32 -> bf16 conversion, 9 jobs in one launch (1024 elems per block).
// ---------------------------------------------------------------------------
struct CvtJobs {
    const float* src[9];
    bf16*        dst[9];
    int          start[10];
};

__global__ __launch_bounds__(256) void cvt_kernel(CvtJobs jobs) {
    int blk = blockIdx.x;
    int j = 0;
#pragma unroll
    for (int i = 1; i < 9; ++i) if (blk >= jobs.start[i]) j = i;
    int off = (blk - jobs.start[j]) * 1024 + threadIdx.x * 4;
    float4 v = *(const float4*)(jobs.src[j] + off);
    union { bf16 h[4]; uint2 u; } p;
    p.h[0] = __float2bfloat16(v.x);
    p.h[1] = __float2bfloat16(v.y);
    p.h[2] = __float2bfloat16(v.z);
    p.h[3] = __float2bfloat16(v.w);
    *(uint2*)(jobs.dst[j] + off) = p.u;
}

// ---------------------------------------------------------------------------
// LDS-staged GEMM body (m97 structure): C = A[M,K] * W[N,K]^T + b1 + b2.
// Tile BM=MT*32 x 128, BK=64, 4 waves (2x2); XOR chunk swizzle on staging.
// obf: store bf16 (else f32). permuteTB: row r=b*64+t stored at t*32+b.
// ---------------------------------------------------------------------------
template <int MT>
__device__ inline void gemm_body(
    bf16* As, bf16* Bs,
    const bf16* __restrict__ A, int lda,
    const bf16* __restrict__ W,
    const float* __restrict__ b1, const float* __restrict__ b2,
    void* C, int ldc, int K, int mt, int nt, int obf, int permuteTB)
{
    int tid = threadIdx.x;
    int w = tid >> 6, lane = tid & 63;
    int lo = lane & 15, hi = lane >> 4;
    int wm = w >> 1, wn = w & 1;

    const bf16* Ab = A + (size_t)(mt * (MT * 32)) * lda;
    const bf16* Wb = W + (size_t)(nt * 128) * K;

    f4v acc[MT][4];
#pragma unroll
    for (int m = 0; m < MT; ++m)
#pragma unroll
        for (int n = 0; n < 4; ++n) acc[m][n] = (f4v){0.f, 0.f, 0.f, 0.f};

    int wbase = tid & 192;

    for (int k0 = 0; k0 < K; k0 += 64) {
#pragma unroll
        for (int i = 0; i < MT; ++i) {
            int ci = i * 256 + tid;
            int row = ci >> 3, c = ci & 7;
            int gc = c ^ (row & 7);
            gload_lds16(Ab + (size_t)row * lda + k0 + gc * 8,
                        As + (i * 256 + wbase) * 8);
        }
#pragma unroll
        for (int i = 0; i < 4; ++i) {
            int ci = i * 256 + tid;
            int row = ci >> 3, c = ci & 7;
            int gc = c ^ (row & 7);
            gload_lds16(Wb + (size_t)row * K + k0 + gc * 8,
                        Bs + (i * 256 + wbase) * 8);
        }
        __syncthreads();

#pragma unroll
        for (int kt = 0; kt < 2; ++kt) {
            s8v a[MT], b[4];
            int sw = ((kt * 4 + hi) ^ (lo & 7)) * 8;
#pragma unroll
            for (int m = 0; m < MT; ++m)
                a[m] = *(const s8v*)(As + (wm * (MT * 16) + m * 16 + lo) * 64 + sw);
#pragma unroll
            for (int n = 0; n < 4; ++n)
                b[n] = *(const s8v*)(Bs + (wn * 64 + n * 16 + lo) * 64 + sw);
#pragma unroll
            for (int m = 0; m < MT; ++m)
#pragma unroll
                for (int n = 0; n < 4; ++n)
                    acc[m][n] = mfma16(a[m], b[n], acc[m][n]);
        }
        __syncthreads();
    }

#pragma unroll
    for (int n = 0; n < 4; ++n) {
        int cc = nt * 128 + wn * 64 + n * 16 + lo;
        float bv = (b1 ? b1[cc] : 0.f) + (b2 ? b2[cc] : 0.f);
#pragma unroll
        for (int m = 0; m < MT; ++m) {
            int rbase = mt * (MT * 32) + wm * (MT * 16) + m * 16 + hi * 4;
#pragma unroll
            for (int i = 0; i < 4; ++i) {
                int r = rbase + i;
                int rr = permuteTB ? ((r & 63) * 32 + (r >> 6)) : r;
                float v = acc[m][n][i] + bv;
                if (obf) ((bf16*)C)[(size_t)rr * ldc + cc] = __float2bfloat16(v);
                else     ((float*)C)[(size_t)rr * ldc + cc] = v;
            }
        }
    }
}

// gemm_pre: blocks [0,128) = f3d (visual@lin_W^T -> feats bf16, K=2048)
//           blocks [128,200) = Uo (objects@U_W^T + U_b + b_attn -> f32, K=512)
__global__ __launch_bounds__(256) void gemm_pre(
    const bf16* visual_b, const bf16* lin_Wb, const float* lin_b,
    const bf16* objects_b, const bf16* U_Wb, const float* U_b,
    const float* b_attn, bf16* feats, float* Uo)
{
    __shared__ bf16 As[64 * 64];
    __shared__ bf16 Bs[128 * 64];
    int blk = blockIdx.x;
    if (blk < 128)
        gemm_body<2>(As, Bs, visual_b, 2048, lin_Wb, lin_b, nullptr,
                     feats, 1024, 2048, blk / 4, blk % 4, 1, 0);
    else {
        int bi = blk - 128;
        gemm_body<2>(As, Bs, objects_b, 512, U_Wb, U_b, b_attn,
                     Uo, 512, 512, bi / 4, bi % 4, 0, 0);
    }
}

// Wf = f3d @ W_W^T + W_b  (f32 out)
__global__ __launch_bounds__(256) void gemm_wf(
    const bf16* feats, const bf16* W_Wb, const float* W_b, float* Wf)
{
    __shared__ bf16 As[64 * 64];
    __shared__ bf16 Bs[128 * 64];
    gemm_body<2>(As, Bs, feats, 1024, W_Wb, W_b, nullptr,
                 Wf, 512, 512, blockIdx.x / 4, blockIdx.x % 4, 0, 0);
}

// gates (both dirs in one launch): out bf16 [dir][64][32][1024]
__global__ __launch_bounds__(256) void gemm_gates(
    const bf16* feats, const bf16* Wih_fb, const bf16* Wih_bb,
    const float* bih_f, const float* bhh_f,
    const float* bih_b, const float* bhh_b, bf16* gatesFB)
{
    __shared__ bf16 As[128 * 64];
    __shared__ bf16 Bs[128 * 64];
    int sel = blockIdx.x >> 7;
    int blk = blockIdx.x & 127;
    gemm_body<4>(As, Bs, feats, 1024,
                 sel ? Wih_bb : Wih_fb,
                 sel ? bih_b : bih_f, sel ? bhh_b : bhh_f,
                 gatesFB + (size_t)sel * 2097152, 1024, 1024,
                 blk / 8, blk % 8, 1, 1);
}

// ---------------------------------------------------------------------------
// Fused additive attention; softmax wave-parallelized.
// ---------------------------------------------------------------------------
__global__ __launch_bounds__(256) void attn_kernel(
    const float* __restrict__ Wf,   // [2048][512]
    const float* __restrict__ Uo,   // [32][36][512]
    const float* __restrict__ wW,   // [512]
    const float* __restrict__ wB,   // [1]
    bf16* __restrict__ feats)       // [2048][1024]
{
    int bt = blockIdx.x, b = bt >> 6;
    int wv = threadIdx.x >> 6, lane = threadIdx.x & 63;
    __shared__ float s_aw[36];

    float wfr[8], wr[8];
    const float* wfrow = Wf + (size_t)bt * 512 + lane * 8;
#pragma unroll
    for (int i = 0; i < 8; ++i) {
        wfr[i] = wfrow[i];
        wr[i]  = wW[lane * 8 + i];
    }
    float wbv = wB[0];

    for (int n = wv; n < 36; n += 4) {
        const float* uo = Uo + ((size_t)b * 36 + n) * 512 + lane * 8;
        float s = 0.f;
#pragma unroll
        for (int i = 0; i < 8; ++i) s += wr[i] * tanh_(wfr[i] + uo[i]);
#pragma unroll
        for (int off = 32; off; off >>= 1) s += __shfl_xor(s, off);
        if (lane == 0) s_aw[n] = s + wbv;
    }
    __syncthreads();
    if (threadIdx.x < 64) {
        float v = (lane < 36) ? s_aw[lane] : -1e30f;
        float mx = v;
#pragma unroll
        for (int off = 32; off; off >>= 1) mx = fmaxf(mx, __shfl_xor(mx, off));
        float e = (lane < 36) ? __expf(v - mx) : 0.f;
        float sum = e;
#pragma unroll
        for (int off = 32; off; off >>= 1) sum += __shfl_xor(sum, off);
        if (lane < 36) s_aw[lane] = e * __builtin_amdgcn_rcpf(sum);
    }
    __syncthreads();

    int h0 = threadIdx.x * 2;
    const float* wf2 = Wf + (size_t)bt * 512 + h0;
    float a0 = wf2[0], a1 = wf2[1];
    for (int n = 0; n < 36; ++n) {
        float awn = s_aw[n];
        const float* uo = Uo + ((size_t)b * 36 + n) * 512 + h0;
        a0 += awn * uo[0];
        a1 += awn * uo[1];
    }
    feats[(size_t)bt * 1024 + 512 + h0]     = __float2bfloat16(a0);
    feats[(size_t)bt * 1024 + 512 + h0 + 1] = __float2bfloat16(a1);
}

// ---------------------------------------------------------------------------
// BiLSTM recurrent part -- SYNC-FREE (R6 post-mortem: stop paying cross-CU
// RTTs; eliminate them). 4 blocks = 2 dirs x 2 batch-groups of 16; each
// block computes its direction's FULL hidden state for its batches, so the
// only synchronization is 2 intra-CU __syncthreads per step.
//
// Whh (one dir, 512KB bf16) = 64 B-frags/wave x 8 waves: 46 frags in VGPRs
// (184 regs) + 18 frags/wave in LDS (144KB, per-lane-linear layout, written
// via global_load_lds). h lives in LDS (16x256 bf16, 8KB) with XOR chunk
// swizzle (chunk ^= batch&7) -> conflict-light b128 reads and b16 writes.
// Gates are bf16 [dir][t][b][1024] and initialize the MFMA accumulator
// directly (C-in = x-projection + biases), saving registers and traffic.
// ---------------------------------------------------------------------------
__global__ __launch_bounds__(512, 2) void lstm_kernel(
    const bf16* __restrict__ WhhF, const bf16* __restrict__ WhhB, // [1024][256]
    const bf16* __restrict__ gates,  // [2][64][32][1024] bf16
    float* __restrict__ out)         // [32][64][512] f32
{
    __shared__ ushort_t sh_h[16 * 256];        // [b][cell] bf16 bits, swizzled
    __shared__ ushort_t sh_whh[8 * 18 * 512];  // per-wave frags, per-lane linear

    int dir = blockIdx.x >> 1;
    int g   = blockIdx.x & 1;
    int w    = threadIdx.x >> 6;
    int lane = threadIdx.x & 63;
    int lo = lane & 15, hi = lane >> 4;

    const bf16* Whh = dir ? WhhB : WhhF;
    const ushort_t* gb = (const ushort_t*)gates + (size_t)dir * 2097152;

    // load Whh fragments: f = q2h*8 + kt; jf = (q2h>>1)*16 + w*2 + (q2h&1)
    s8v whhR[46];
#pragma unroll
    for (int q2h = 0; q2h < 8; ++q2h) {
        int jf = (q2h >> 1) * 16 + w * 2 + (q2h & 1);
        const bf16* wp = Whh + (size_t)(jf * 16 + lo) * 256 + hi * 8;
#pragma unroll
        for (int kt = 0; kt < 8; ++kt) {
            int f = q2h * 8 + kt;
            if (f < 46) whhR[f] = *(const s8v*)(wp + kt * 32);
            else gload_lds16(wp + kt * 32,
                             (bf16*)&sh_whh[(w * 18 + (f - 46)) * 512]);
        }
    }

    // h(0) = 0
    for (int x = threadIdx.x; x < 4096; x += 512) sh_h[x] = 0;

    float cst[2][4] = {{0.f,0.f,0.f,0.f},{0.f,0.f,0.f,0.f}};
    __syncthreads();   // whh-LDS arrival (vmcnt) + h(0) visible

    for (int t = 0; t < 64; ++t) {
        int tp = dir ? (63 - t) : t;

        // acc init = gates (x-projection + biases), bf16 -> f32
        f4v acc[8];
        {
            const ushort_t* gt = gb + (size_t)tp * 32768 + (g * 16) * 1024;
#pragma unroll
            for (int q = 0; q < 4; ++q)
#pragma unroll
                for (int half = 0; half < 2; ++half) {
                    int col = q * 256 + w * 32 + half * 16 + lo;
#pragma unroll
                    for (int i = 0; i < 4; ++i)
                        acc[q * 2 + half][i] = bf2f(gt[(hi * 4 + i) * 1024 + col]);
                }
        }

        // MFMA: acc += h(t) x Whh
#pragma unroll
        for (int kt = 0; kt < 8; ++kt) {
            s8v a = *(const s8v*)&sh_h[lo * 256 + (((kt * 4 + hi) ^ (lo & 7)) * 8)];
#pragma unroll
            for (int q2h = 0; q2h < 8; ++q2h) {
                int f = q2h * 8 + kt;
                if (f < 46) {
                    acc[q2h] = mfma16(a, whhR[f], acc[q2h]);
                } else {
                    s8v bb = *(const s8v*)&sh_whh[(w * 18 + (f - 46)) * 512 + lane * 8];
                    acc[q2h] = mfma16(a, bb, acc[q2h]);
                }
            }
        }

        // activations
        float hv[2][4];
#pragma unroll
        for (int half = 0; half < 2; ++half)
#pragma unroll
            for (int i = 0; i < 4; ++i) {
                float xi = acc[0 + half][i];
                float xf = acc[2 + half][i];
                float xg = acc[4 + half][i];
                float xo = acc[6 + half][i];
                float c = sigf(xf) * cst[half][i] + sigf(xi) * tanh_(xg);
                cst[half][i] = c;
                hv[half][i] = sigf(xo) * tanh_(c);
            }

        __syncthreads();   // all waves done reading h(t)

        // write h(t+1) (swizzled) + out
#pragma unroll
        for (int half = 0; half < 2; ++half)
#pragma unroll
            for (int i = 0; i < 4; ++i) {
                int b = hi * 4 + i;
                int c = w * 32 + half * 16 + lo;
                int slot = (c >> 3) ^ (b & 7);
                sh_h[b * 256 + slot * 8 + (lo & 7)] = f2bf(hv[half][i]);
                out[((size_t)(g * 16 + b) * 64 + tp) * 512 + dir * 256 + c] =
                    hv[half][i];
            }

        __syncthreads();   // h(t+1) visible
    }
}

// ---------------------------------------------------------------------------
// action = max over T of output; action_semantics = action @ fc_W^T + fc_b
// ---------------------------------------------------------------------------
__global__ __launch_bounds__(256) void final_kernel(
    const float* __restrict__ out,   // [32][64][512]
    const float* __restrict__ fcW,   // [300][512]
    const float* __restrict__ fcb,   // [300]
    float* __restrict__ osem)        // [32][300]
{
    int b = blockIdx.x, tid = threadIdx.x;
    __shared__ float act[512];
    for (int h = tid; h < 512; h += 256) {
        float m = -1e30f;
        const float* p = out + (size_t)b * 64 * 512 + h;
#pragma unroll 8
        for (int t = 0; t < 64; ++t) m = fmaxf(m, p[t * 512]);
        act[h] = m;
    }
    __syncthreads();
    int wv = tid >> 6, lane = tid & 63;
    for (int s = wv; s < 300; s += 4) {
        const float* wrow = fcW + (size_t)s * 512 + lane * 8;
        float a = 0.f;
#pragma unroll
        for (int i = 0; i < 8; ++i) a += act[lane * 8 + i] * wrow[i];
#pragma unroll
        for (int off = 32; off; off >>= 1) a += __shfl_xor(a, off);
        if (lane == 0) osem[b * 300 + s] = a + fcb[s];
    }
}

// ---------------------------------------------------------------------------
extern "C" void kernel_launch(void* const* d_in, const int* in_sizes, int n_in,
                              void* d_out, int out_size, void* d_ws, size_t ws_size,
                              hipStream_t stream)
{
    const float* visual  = (const float*)d_in[0];
    const float* objects = (const float*)d_in[1];
    const float* lin_W   = (const float*)d_in[2];
    const float* lin_b   = (const float*)d_in[3];
    const float* W_W     = (const float*)d_in[4];
    const float* W_b     = (const float*)d_in[5];
    const float* U_W     = (const float*)d_in[6];
    const float* U_b     = (const float*)d_in[7];
    const float* b_attn  = (const float*)d_in[8];
    const float* w_W     = (const float*)d_in[9];
    const float* w_b     = (const float*)d_in[10];
    const float* Wih_f   = (const float*)d_in[11];
    const float* Whh_f   = (const float*)d_in[12];
    const float* bih_f   = (const float*)d_in[13];
    const float* bhh_f   = (const float*)d_in[14];
    const float* Wih_b   = (const float*)d_in[15];
    const float* Whh_b   = (const float*)d_in[16];
    const float* bih_b   = (const float*)d_in[17];
    const float* bhh_b   = (const float*)d_in[18];
    const float* fc_W    = (const float*)d_in[19];
    const float* fc_b    = (const float*)d_in[20];

    char* ws = (char*)d_ws;
    size_t o = 0;
    bf16*   feats   = (bf16*)(ws + o);   o += (size_t)2048 * 1024 * 2;
    float*  Wf      = (float*)(ws + o);  o += (size_t)2048 * 512 * 4;
    float*  Uo      = (float*)(ws + o);  o += (size_t)1152 * 512 * 4;
    bf16*   gatesFB = (bf16*)(ws + o);   o += (size_t)2 * 2097152 * 2;  // bf16
    bf16*  visual_b  = (bf16*)(ws + o); o += (size_t)4194304 * 2;
    bf16*  objects_b = (bf16*)(ws + o); o += (size_t)589824 * 2;
    bf16*  lin_Wb    = (bf16*)(ws + o); o += (size_t)1048576 * 2;
    bf16*  W_Wb      = (bf16*)(ws + o); o += (size_t)262144 * 2;
    bf16*  U_Wb      = (bf16*)(ws + o); o += (size_t)262144 * 2;
    bf16*  Wih_fb    = (bf16*)(ws + o); o += (size_t)1048576 * 2;
    bf16*  Whh_fb    = (bf16*)(ws + o); o += (size_t)262144 * 2;
    bf16*  Wih_bb    = (bf16*)(ws + o); o += (size_t)1048576 * 2;
    bf16*  Whh_bb    = (bf16*)(ws + o); o += (size_t)262144 * 2;

    CvtJobs cj;
    const float* srcs[9] = {visual, objects, lin_W, W_W, U_W, Wih_f, Whh_f, Wih_b, Whh_b};
    bf16* dsts[9] = {visual_b, objects_b, lin_Wb, W_Wb, U_Wb, Wih_fb, Whh_fb, Wih_bb, Whh_bb};
    int ns[9] = {4194304, 589824, 1048576, 262144, 262144, 1048576, 262144, 1048576, 262144};
    int acc_b = 0;
    for (int i = 0; i < 9; ++i) {
        cj.src[i] = srcs[i];
        cj.dst[i] = dsts[i];
        cj.start[i] = acc_b;
        acc_b += ns[i] / 1024;
    }
    cj.start[9] = acc_b;

    dim3 blk(256);
    cvt_kernel<<<acc_b, blk, 0, stream>>>(cj);

    // f3d (128 blocks) + Uo (72 blocks) in one launch
    gemm_pre<<<200, blk, 0, stream>>>(visual_b, lin_Wb, lin_b,
                                      objects_b, U_Wb, U_b, b_attn, feats, Uo);
    // Wf = f3d@W_W^T + W_b
    gemm_wf<<<128, blk, 0, stream>>>(feats, W_Wb, W_b, Wf);
    // fused attention -> feats[:, 512:]
    attn_kernel<<<2048, blk, 0, stream>>>(Wf, Uo, w_W, w_b, feats);
    // gate input projections, both dirs, one launch -> bf16 [2][64][32][1024]
    gemm_gates<<<256, blk, 0, stream>>>(feats, Wih_fb, Wih_bb,
                                        bih_f, bhh_f, bih_b, bhh_b, gatesFB);
    // sync-free recurrent BiLSTM -> d_out[0 .. 1048575]
    lstm_kernel<<<4, dim3(512), 0, stream>>>(Whh_fb, Whh_bb, gatesFB,
                                             (float*)d_out);
    // action max + fc -> d_out[1048576 ..]
    final_kernel<<<32, blk, 0, stream>>>((float*)d_out, fc_W, fc_b,
                                         (float*)d_out + 1048576);
}

// Round 9
// 698.412 us; speedup vs baseline: 1.1206x; 1.1206x over previous
//
#include <hip/hip_runtime.h>
#include <hip/hip_bf16.h>
#include <type_traits>

// Problem: PredicateLevelEncoder  B=32 T=64 N=36 VD=2048 H=512 S=300 Hc=256
// Device tensors are f32; MFMA operands converted to bf16 in ws; f32 outputs.

typedef __hip_bfloat16 bf16;
typedef unsigned int uint32;
typedef __attribute__((ext_vector_type(8))) short s8v;     // 8 bf16
typedef __attribute__((ext_vector_type(4))) float f4v;     // mfma accum
typedef __attribute__((ext_vector_type(4))) uint32 u32x4;  // tagged loads
typedef __attribute__((ext_vector_type(4))) int   i32x4;   // flag loads

__device__ inline f4v mfma16(s8v a, s8v b, f4v c) {
    return __builtin_amdgcn_mfma_f32_16x16x32_bf16(a, b, c, 0, 0, 0);
}
__device__ inline float sigf(float x) {
    return __builtin_amdgcn_rcpf(1.f + __expf(-x));
}
__device__ inline float tanh_(float x) {
    return 1.f - 2.f * __builtin_amdgcn_rcpf(1.f + __expf(2.f * x));
}
__device__ inline uint32 pack2(uint32 d0, uint32 d1) {
    // result = d0.low16 | d1.low16<<16  (R5-validated)
    return __builtin_amdgcn_perm(d1, d0, 0x05040100u);
}
__device__ inline void gload_lds16(const bf16* g, bf16* l) {
    __builtin_amdgcn_global_load_lds(
        (const __attribute__((address_space(1))) void*)g,
        (__attribute__((address_space(3))) void*)l, 16, 0, 0);
}

// ---------------------------------------------------------------------------
// Fused f32 -> bf16 conversion, 9 jobs in one launch (1024 elems per block).
// ---------------------------------------------------------------------------
struct CvtJobs {
    const float* src[9];
    bf16*        dst[9];
    int          start[10];
};

__global__ __launch_bounds__(256) void cvt_kernel(CvtJobs jobs) {
    int blk = blockIdx.x;
    int j = 0;
#pragma unroll
    for (int i = 1; i < 9; ++i) if (blk >= jobs.start[i]) j = i;
    int off = (blk - jobs.start[j]) * 1024 + threadIdx.x * 4;
    float4 v = *(const float4*)(jobs.src[j] + off);
    union { bf16 h[4]; uint2 u; } p;
    p.h[0] = __float2bfloat16(v.x);
    p.h[1] = __float2bfloat16(v.y);
    p.h[2] = __float2bfloat16(v.z);
    p.h[3] = __float2bfloat16(v.w);
    *(uint2*)(jobs.dst[j] + off) = p.u;
}

// ---------------------------------------------------------------------------
// LDS-staged GEMM body: C = A[M,K] * W[N,K]^T + b1 + b2 (f32 biases).
// Tile BM=MT*32 x 128, BK=64, 4 waves (2x2); XOR chunk swizzle on staging.
// ---------------------------------------------------------------------------
template <int MT>
__device__ inline void gemm_body(
    bf16* As, bf16* Bs,
    const bf16* __restrict__ A, int lda,
    const bf16* __restrict__ W,
    const float* __restrict__ b1, const float* __restrict__ b2,
    void* C, int ldc, int K, int mt, int nt, int obf, int permuteTB)
{
    int tid = threadIdx.x;
    int w = tid >> 6, lane = tid & 63;
    int lo = lane & 15, hi = lane >> 4;
    int wm = w >> 1, wn = w & 1;

    const bf16* Ab = A + (size_t)(mt * (MT * 32)) * lda;
    const bf16* Wb = W + (size_t)(nt * 128) * K;

    f4v acc[MT][4];
#pragma unroll
    for (int m = 0; m < MT; ++m)
#pragma unroll
        for (int n = 0; n < 4; ++n) acc[m][n] = (f4v){0.f, 0.f, 0.f, 0.f};

    int wbase = tid & 192;

    for (int k0 = 0; k0 < K; k0 += 64) {
#pragma unroll
        for (int i = 0; i < MT; ++i) {
            int ci = i * 256 + tid;
            int row = ci >> 3, c = ci & 7;
            int gc = c ^ (row & 7);
            gload_lds16(Ab + (size_t)row * lda + k0 + gc * 8,
                        As + (i * 256 + wbase) * 8);
        }
#pragma unroll
        for (int i = 0; i < 4; ++i) {
            int ci = i * 256 + tid;
            int row = ci >> 3, c = ci & 7;
            int gc = c ^ (row & 7);
            gload_lds16(Wb + (size_t)row * K + k0 + gc * 8,
                        Bs + (i * 256 + wbase) * 8);
        }
        __syncthreads();

#pragma unroll
        for (int kt = 0; kt < 2; ++kt) {
            s8v a[MT], b[4];
            int sw = ((kt * 4 + hi) ^ (lo & 7)) * 8;
#pragma unroll
            for (int m = 0; m < MT; ++m)
                a[m] = *(const s8v*)(As + (wm * (MT * 16) + m * 16 + lo) * 64 + sw);
#pragma unroll
            for (int n = 0; n < 4; ++n)
                b[n] = *(const s8v*)(Bs + (wn * 64 + n * 16 + lo) * 64 + sw);
#pragma unroll
            for (int m = 0; m < MT; ++m)
#pragma unroll
                for (int n = 0; n < 4; ++n)
                    acc[m][n] = mfma16(a[m], b[n], acc[m][n]);
        }
        __syncthreads();
    }

#pragma unroll
    for (int n = 0; n < 4; ++n) {
        int cc = nt * 128 + wn * 64 + n * 16 + lo;
        float bv = (b1 ? b1[cc] : 0.f) + (b2 ? b2[cc] : 0.f);
#pragma unroll
        for (int m = 0; m < MT; ++m) {
            int rbase = mt * (MT * 32) + wm * (MT * 16) + m * 16 + hi * 4;
#pragma unroll
            for (int i = 0; i < 4; ++i) {
                int r = rbase + i;
                int rr = permuteTB ? ((r & 63) * 32 + (r >> 6)) : r;
                float v = acc[m][n][i] + bv;
                if (obf) ((bf16*)C)[(size_t)rr * ldc + cc] = __float2bfloat16(v);
                else     ((float*)C)[(size_t)rr * ldc + cc] = v;
            }
        }
    }
}

// blocks [0,128) = f3d (visual@lin_W^T -> feats bf16, K=2048)
// blocks [128,200) = Uo (objects@U_W^T + U_b + b_attn -> f32, K=512)
__global__ __launch_bounds__(256) void gemm_pre(
    const bf16* visual_b, const bf16* lin_Wb, const float* lin_b,
    const bf16* objects_b, const bf16* U_Wb, const float* U_b,
    const float* b_attn, bf16* feats, float* Uo)
{
    __shared__ bf16 As[64 * 64];
    __shared__ bf16 Bs[128 * 64];
    int blk = blockIdx.x;
    if (blk < 128)
        gemm_body<2>(As, Bs, visual_b, 2048, lin_Wb, lin_b, nullptr,
                     feats, 1024, 2048, blk / 4, blk % 4, 1, 0);
    else {
        int bi = blk - 128;
        gemm_body<2>(As, Bs, objects_b, 512, U_Wb, U_b, b_attn,
                     Uo, 512, 512, bi / 4, bi % 4, 0, 0);
    }
}

__global__ __launch_bounds__(256) void gemm_wf(
    const bf16* feats, const bf16* W_Wb, const float* W_b, float* Wf)
{
    __shared__ bf16 As[64 * 64];
    __shared__ bf16 Bs[128 * 64];
    gemm_body<2>(As, Bs, feats, 1024, W_Wb, W_b, nullptr,
                 Wf, 512, 512, blockIdx.x / 4, blockIdx.x % 4, 0, 0);
}

// gates (both dirs in one launch): f32 out [64][32][1024] per dir
__global__ __launch_bounds__(256) void gemm_gates(
    const bf16* feats, const bf16* Wih_fb, const bf16* Wih_bb,
    const float* bih_f, const float* bhh_f,
    const float* bih_b, const float* bhh_b,
    float* gatesF, float* gatesB)
{
    __shared__ bf16 As[128 * 64];
    __shared__ bf16 Bs[128 * 64];
    int sel = blockIdx.x >> 7;
    int blk = blockIdx.x & 127;
    gemm_body<4>(As, Bs, feats, 1024,
                 sel ? Wih_bb : Wih_fb,
                 sel ? bih_b : bih_f, sel ? bhh_b : bhh_f,
                 sel ? gatesB : gatesF, 1024, 1024,
                 blk / 8, blk % 8, 0, 1);
}

// ---------------------------------------------------------------------------
// Fused additive attention, Uo[b] staged ONCE in LDS per block (74KB);
// grid 256 = 32 batches x 8 t-groups of 8.
// ---------------------------------------------------------------------------
__global__ __launch_bounds__(256) void attn_kernel(
    const float* __restrict__ Wf,   // [2048][512]
    const float* __restrict__ Uo,   // [32][36][512]
    const float* __restrict__ wW,   // [512]
    const float* __restrict__ wB,   // [1]
    bf16* __restrict__ feats)       // [2048][1024]
{
    __shared__ float sh_uo[36 * 512];
    __shared__ float s_aw[36];
    int b = blockIdx.x >> 3, tg = blockIdx.x & 7;
    int tid = threadIdx.x, wv = tid >> 6, lane = tid & 63;

    {
        const float4* src = (const float4*)(Uo + (size_t)b * 18432);
        float4* dst = (float4*)sh_uo;
        for (int i = tid; i < 4608; i += 256) dst[i] = src[i];
    }
    float wr[8];
#pragma unroll
    for (int i = 0; i < 8; ++i) wr[i] = wW[lane * 8 + i];
    float wbv = wB[0];
    __syncthreads();

    for (int ts = 0; ts < 8; ++ts) {
        int bt = b * 64 + tg * 8 + ts;
        const float* wfrow = Wf + (size_t)bt * 512;
        float wfr[8];
#pragma unroll
        for (int i = 0; i < 8; ++i) wfr[i] = wfrow[lane * 8 + i];

        for (int n = wv; n < 36; n += 4) {
            const float* uo = sh_uo + n * 512 + lane * 8;
            float s = 0.f;
#pragma unroll
            for (int i = 0; i < 8; ++i) s += wr[i] * tanh_(wfr[i] + uo[i]);
#pragma unroll
            for (int off = 32; off; off >>= 1) s += __shfl_xor(s, off);
            if (lane == 0) s_aw[n] = s + wbv;
        }
        __syncthreads();
        if (tid < 64) {
            float v = (lane < 36) ? s_aw[lane] : -1e30f;
            float mx = v;
#pragma unroll
            for (int off = 32; off; off >>= 1) mx = fmaxf(mx, __shfl_xor(mx, off));
            float e = (lane < 36) ? __expf(v - mx) : 0.f;
            float sum = e;
#pragma unroll
            for (int off = 32; off; off >>= 1) sum += __shfl_xor(sum, off);
            if (lane < 36) s_aw[lane] = e * __builtin_amdgcn_rcpf(sum);
        }
        __syncthreads();

        int h0 = tid * 2;
        float a0 = wfrow[h0], a1 = wfrow[h0 + 1];
        for (int n = 0; n < 36; ++n) {
            float awn = s_aw[n];
            a0 += awn * sh_uo[n * 512 + h0];
            a1 += awn * sh_uo[n * 512 + h0 + 1];
        }
        feats[(size_t)bt * 1024 + 512 + h0]     = __float2bfloat16(a0);
        feats[(size_t)bt * 1024 + 512 + h0 + 1] = __float2bfloat16(a1);
        __syncthreads();
    }
}

// ---------------------------------------------------------------------------
// BiLSTM ring (R6 structure) + speculative tagged h.
// 8 blocks = 2 batch-groups x 4 j-slices; each block does BOTH dirs.
// h stored 1 bf16/dword with step-tag in high16 (tear-proof). After setting
// its own flag, each block speculatively loads data+flags together; tag-hit
// + flag-hit skips the poll RTT. Tag-miss: poll flags>=t+2, reload once
// (clean: overwrite of h(t+1) needs flag-permission t+3 we haven't given).
// Flag check doubles as overwrite-permission (R6's anti-overwrite chain).
// ---------------------------------------------------------------------------
__device__ inline void spec_load(const uint32* pF, const uint32* pB,
                                 const int* pf, u32x4* rw, i32x4* fl)
{
    asm volatile(
        "global_load_dwordx4 %0, %33, off sc1\n\t"
        "global_load_dwordx4 %1, %33, off offset:16 sc1\n\t"
        "global_load_dwordx4 %2, %33, off offset:128 sc1\n\t"
        "global_load_dwordx4 %3, %33, off offset:144 sc1\n\t"
        "global_load_dwordx4 %4, %33, off offset:256 sc1\n\t"
        "global_load_dwordx4 %5, %33, off offset:272 sc1\n\t"
        "global_load_dwordx4 %6, %33, off offset:384 sc1\n\t"
        "global_load_dwordx4 %7, %33, off offset:400 sc1\n\t"
        "global_load_dwordx4 %8, %33, off offset:512 sc1\n\t"
        "global_load_dwordx4 %9, %33, off offset:528 sc1\n\t"
        "global_load_dwordx4 %10, %33, off offset:640 sc1\n\t"
        "global_load_dwordx4 %11, %33, off offset:656 sc1\n\t"
        "global_load_dwordx4 %12, %33, off offset:768 sc1\n\t"
        "global_load_dwordx4 %13, %33, off offset:784 sc1\n\t"
        "global_load_dwordx4 %14, %33, off offset:896 sc1\n\t"
        "global_load_dwordx4 %15, %33, off offset:912 sc1\n\t"
        "global_load_dwordx4 %16, %34, off sc1\n\t"
        "global_load_dwordx4 %17, %34, off offset:16 sc1\n\t"
        "global_load_dwordx4 %18, %34, off offset:128 sc1\n\t"
        "global_load_dwordx4 %19, %34, off offset:144 sc1\n\t"
        "global_load_dwordx4 %20, %34, off offset:256 sc1\n\t"
        "global_load_dwordx4 %21, %34, off offset:272 sc1\n\t"
        "global_load_dwordx4 %22, %34, off offset:384 sc1\n\t"
        "global_load_dwordx4 %23, %34, off offset:400 sc1\n\t"
        "global_load_dwordx4 %24, %34, off offset:512 sc1\n\t"
        "global_load_dwordx4 %25, %34, off offset:528 sc1\n\t"
        "global_load_dwordx4 %26, %34, off offset:640 sc1\n\t"
        "global_load_dwordx4 %27, %34, off offset:656 sc1\n\t"
        "global_load_dwordx4 %28, %34, off offset:768 sc1\n\t"
        "global_load_dwordx4 %29, %34, off offset:784 sc1\n\t"
        "global_load_dwordx4 %30, %34, off offset:896 sc1\n\t"
        "global_load_dwordx4 %31, %34, off offset:912 sc1\n\t"
        "global_load_dwordx4 %32, %35, off sc1\n\t"
        "s_waitcnt vmcnt(0)"
        : "=v"(rw[0]), "=v"(rw[1]), "=v"(rw[2]), "=v"(rw[3]),
          "=v"(rw[4]), "=v"(rw[5]), "=v"(rw[6]), "=v"(rw[7]),
          "=v"(rw[8]), "=v"(rw[9]), "=v"(rw[10]), "=v"(rw[11]),
          "=v"(rw[12]), "=v"(rw[13]), "=v"(rw[14]), "=v"(rw[15]),
          "=v"(rw[16]), "=v"(rw[17]), "=v"(rw[18]), "=v"(rw[19]),
          "=v"(rw[20]), "=v"(rw[21]), "=v"(rw[22]), "=v"(rw[23]),
          "=v"(rw[24]), "=v"(rw[25]), "=v"(rw[26]), "=v"(rw[27]),
          "=v"(rw[28]), "=v"(rw[29]), "=v"(rw[30]), "=v"(rw[31]),
          "=v"(*fl)
        : "v"(pF), "v"(pB), "v"(pf)
        : "memory");
}

__device__ inline void poll_flags(const int* pf, int need) {
    for (;;) {
        i32x4 f;
        asm volatile("global_load_dwordx4 %0, %1, off sc1\n\t"
                     "s_waitcnt vmcnt(0)"
                     : "=v"(f) : "v"(pf) : "memory");
        if (f[0] >= need && f[1] >= need && f[2] >= need && f[3] >= need)
            break;
    }
}

__global__ __launch_bounds__(256, 1) void lstm_kernel(
    const bf16* __restrict__ WhhF, const bf16* __restrict__ WhhB, // [1024][256]
    const float* __restrict__ gatesF, const float* __restrict__ gatesB, // [64][32][1024]
    uint32* __restrict__ hx,  // [2 g][2 dir][2 slot][16][256] tagged dwords
    float* __restrict__ out,  // [32][64][512]
    int* __restrict__ bar)    // [2 g][16]; flags at [g*16 + pid]
{
    int bi  = blockIdx.x;
    int g   = bi >> 2;
    int pid = bi & 3;
    int jb  = pid * 64;
    int wv = threadIdx.x >> 6, lane = threadIdx.x & 63;
    int lo = lane & 15, hi = lane >> 4;
    int j0 = jb + wv * 16;

    uint32* hxg  = hx + (size_t)g * 16384;   // dir*8192 + slot*4096 + b*256 + j
    int* flags = bar + g * 16;

    // Whh fragments for BOTH dirs (64 s8v; MFMA-only use -> AGPR-friendly)
    s8v whh[2][4][8];
#pragma unroll
    for (int q = 0; q < 4; ++q)
#pragma unroll
        for (int kt = 0; kt < 8; ++kt) {
            whh[0][q][kt] = *(const s8v*)(WhhF + (size_t)(q * 256 + j0 + lo) * 256 + kt * 32 + hi * 8);
            whh[1][q][kt] = *(const s8v*)(WhhB + (size_t)(q * 256 + j0 + lo) * 256 + kt * 32 + hi * 8);
        }

    // init slot 0, both dirs, own j-slice: dword = tag0|bf16(0) = 0
    for (int x = threadIdx.x; x < 2048; x += 256) {
        int d = x >> 10, b = (x >> 6) & 15, j = jb + (x & 63);
        __hip_atomic_store(&hxg[d * 8192 + b * 256 + j], 0u,
                           __ATOMIC_RELAXED, __HIP_MEMORY_SCOPE_AGENT);
    }
    __syncthreads();   // drain init stores
    if (threadIdx.x == 0)
        __hip_atomic_store(&flags[pid], 1, __ATOMIC_RELAXED,
                           __HIP_MEMORY_SCOPE_AGENT);

    // prologue: poll then load h(0) (slot 0) -- guaranteed clean
    u32x4 rw[32];
    i32x4 fl;
    poll_flags(flags, 1);
    {
        const uint32* pF = hxg + lo * 256 + hi * 8;
        spec_load(pF, pF + 8192, flags, rw, &fl);
    }
    s8v aF[16];
#pragma unroll
    for (int kt = 0; kt < 8; ++kt)
#pragma unroll
        for (int d = 0; d < 2; ++d) {
            u32x4 A0 = rw[d * 16 + kt * 2];
            u32x4 A1 = rw[d * 16 + kt * 2 + 1];
            union { uint32 u[4]; s8v v; } tt;
            tt.u[0] = pack2(A0[0], A0[1]);
            tt.u[1] = pack2(A0[2], A0[3]);
            tt.u[2] = pack2(A1[0], A1[1]);
            tt.u[3] = pack2(A1[2], A1[3]);
            aF[d * 8 + kt] = tt.v;
        }

    float cstf[4] = {0.f,0.f,0.f,0.f}, cstb[4] = {0.f,0.f,0.f,0.f};

    for (int t = 0; t < 64; ++t) {
        int tpF = t, tpB = 63 - t;
        int slot = (t + 1) & 1;
        uint32 tagw = (uint32)(t + 1) << 16;

        // gate inputs both dirs (f32, L2-warm)
        float gvf[4][4], gvb[4][4];
#pragma unroll
        for (int i = 0; i < 4; ++i) {
            int bg = g * 16 + hi * 4 + i;
#pragma unroll
            for (int q = 0; q < 4; ++q) {
                gvf[q][i] = gatesF[(size_t)tpF * 32768 + bg * 1024 + q * 256 + j0 + lo];
                gvb[q][i] = gatesB[(size_t)tpB * 32768 + bg * 1024 + q * 256 + j0 + lo];
            }
        }

        // ---- forward ----
        float hvf[4];
        {
            f4v acc[4];
#pragma unroll
            for (int q = 0; q < 4; ++q) acc[q] = (f4v){0.f,0.f,0.f,0.f};
#pragma unroll
            for (int kt = 0; kt < 8; ++kt)
#pragma unroll
                for (int q = 0; q < 4; ++q)
                    acc[q] = mfma16(aF[kt], whh[0][q][kt], acc[q]);
#pragma unroll
            for (int i = 0; i < 4; ++i) {
                float xi = acc[0][i] + gvf[0][i];
                float xf = acc[1][i] + gvf[1][i];
                float xg = acc[2][i] + gvf[2][i];
                float xo = acc[3][i] + gvf[3][i];
                float c = sigf(xf) * cstf[i] + sigf(xi) * tanh_(xg);
                cstf[i] = c;
                hvf[i] = sigf(xo) * tanh_(c);
            }
        }
        if (t < 63) {
            uint32* hw = hxg + slot * 4096;
#pragma unroll
            for (int i = 0; i < 4; ++i)
                __hip_atomic_store(&hw[(hi * 4 + i) * 256 + j0 + lo],
                    tagw | (uint32)__bfloat16_as_ushort(__float2bfloat16(hvf[i])),
                    __ATOMIC_RELAXED, __HIP_MEMORY_SCOPE_AGENT);
        }

        // ---- backward ----
        float hvb[4];
        {
            f4v acc[4];
#pragma unroll
            for (int q = 0; q < 4; ++q) acc[q] = (f4v){0.f,0.f,0.f,0.f};
#pragma unroll
            for (int kt = 0; kt < 8; ++kt)
#pragma unroll
                for (int q = 0; q < 4; ++q)
                    acc[q] = mfma16(aF[8 + kt], whh[1][q][kt], acc[q]);
#pragma unroll
            for (int i = 0; i < 4; ++i) {
                float xi = acc[0][i] + gvb[0][i];
                float xf = acc[1][i] + gvb[1][i];
                float xg = acc[2][i] + gvb[2][i];
                float xo = acc[3][i] + gvb[3][i];
                float c = sigf(xf) * cstb[i] + sigf(xi) * tanh_(xg);
                cstb[i] = c;
                hvb[i] = sigf(xo) * tanh_(c);
            }
        }
        if (t < 63) {
            uint32* hw = hxg + 8192 + slot * 4096;
#pragma unroll
            for (int i = 0; i < 4; ++i)
                __hip_atomic_store(&hw[(hi * 4 + i) * 256 + j0 + lo],
                    tagw | (uint32)__bfloat16_as_ushort(__float2bfloat16(hvb[i])),
                    __ATOMIC_RELAXED, __HIP_MEMORY_SCOPE_AGENT);
        }

        __syncthreads();   // drain h stores (out stores not yet issued)
        if (threadIdx.x == 0)
            __hip_atomic_store(&flags[pid], t + 2, __ATOMIC_RELAXED,
                               __HIP_MEMORY_SCOPE_AGENT);

        if (t < 63) {
            // speculative data+flag load, then out stores overlap the check
            const uint32* pF = hxg + slot * 4096 + lo * 256 + hi * 8;
            spec_load(pF, pF + 8192, flags, rw, &fl);
#pragma unroll
            for (int i = 0; i < 4; ++i) {
                int bg = g * 16 + hi * 4 + i;
                out[((size_t)bg * 64 + tpF) * 512 + j0 + lo]       = hvf[i];
                out[((size_t)bg * 64 + tpB) * 512 + 256 + j0 + lo] = hvb[i];
            }
            uint32 bad = 0;
#pragma unroll
            for (int q = 0; q < 32; ++q)
                bad |= (rw[q][0] ^ tagw) | (rw[q][1] ^ tagw) |
                       (rw[q][2] ^ tagw) | (rw[q][3] ^ tagw);
            int tagok  = !__any(bad >> 16);
            int need   = t + 2;
            int flagok = (fl[0] >= need) && (fl[1] >= need) &&
                         (fl[2] >= need) && (fl[3] >= need);
            if (!(tagok && flagok)) {
                poll_flags(flags, need);          // wave-local, monotone
                if (!tagok)
                    spec_load(pF, pF + 8192, flags, rw, &fl);  // clean reload
            }
#pragma unroll
            for (int kt = 0; kt < 8; ++kt)
#pragma unroll
                for (int d = 0; d < 2; ++d) {
                    u32x4 A0 = rw[d * 16 + kt * 2];
                    u32x4 A1 = rw[d * 16 + kt * 2 + 1];
                    union { uint32 u[4]; s8v v; } tt;
                    tt.u[0] = pack2(A0[0], A0[1]);
                    tt.u[1] = pack2(A0[2], A0[3]);
                    tt.u[2] = pack2(A1[0], A1[1]);
                    tt.u[3] = pack2(A1[2], A1[3]);
                    aF[d * 8 + kt] = tt.v;
                }
        } else {
#pragma unroll
            for (int i = 0; i < 4; ++i) {
                int bg = g * 16 + hi * 4 + i;
                out[((size_t)bg * 64 + tpF) * 512 + j0 + lo]       = hvf[i];
                out[((size_t)bg * 64 + tpB) * 512 + 256 + j0 + lo] = hvb[i];
            }
        }
    }
}

// ---------------------------------------------------------------------------
// action = max over T of output; action_semantics = action @ fc_W^T + fc_b
// ---------------------------------------------------------------------------
__global__ __launch_bounds__(256) void final_kernel(
    const float* __restrict__ out,   // [32][64][512]
    const float* __restrict__ fcW,   // [300][512]
    const float* __restrict__ fcb,   // [300]
    float* __restrict__ osem)        // [32][300]
{
    int b = blockIdx.x, tid = threadIdx.x;
    __shared__ float act[512];
    for (int h = tid; h < 512; h += 256) {
        float m = -1e30f;
        const float* p = out + (size_t)b * 64 * 512 + h;
#pragma unroll 8
        for (int t = 0; t < 64; ++t) m = fmaxf(m, p[t * 512]);
        act[h] = m;
    }
    __syncthreads();
    int wv = tid >> 6, lane = tid & 63;
    for (int s = wv; s < 300; s += 4) {
        const float* wrow = fcW + (size_t)s * 512 + lane * 8;
        float a = 0.f;
#pragma unroll
        for (int i = 0; i < 8; ++i) a += act[lane * 8 + i] * wrow[i];
#pragma unroll
        for (int off = 32; off; off >>= 1) a += __shfl_xor(a, off);
        if (lane == 0) osem[b * 300 + s] = a + fcb[s];
    }
}

// ---------------------------------------------------------------------------
extern "C" void kernel_launch(void* const* d_in, const int* in_sizes, int n_in,
                              void* d_out, int out_size, void* d_ws, size_t ws_size,
                              hipStream_t stream)
{
    const float* visual  = (const float*)d_in[0];
    const float* objects = (const float*)d_in[1];
    const float* lin_W   = (const float*)d_in[2];
    const float* lin_b   = (const float*)d_in[3];
    const float* W_W     = (const float*)d_in[4];
    const float* W_b     = (const float*)d_in[5];
    const float* U_W     = (const float*)d_in[6];
    const float* U_b     = (const float*)d_in[7];
    const float* b_attn  = (const float*)d_in[8];
    const float* w_W     = (const float*)d_in[9];
    const float* w_b     = (const float*)d_in[10];
    const float* Wih_f   = (const float*)d_in[11];
    const float* Whh_f   = (const float*)d_in[12];
    const float* bih_f   = (const float*)d_in[13];
    const float* bhh_f   = (const float*)d_in[14];
    const float* Wih_b   = (const float*)d_in[15];
    const float* Whh_b   = (const float*)d_in[16];
    const float* bih_b   = (const float*)d_in[17];
    const float* bhh_b   = (const float*)d_in[18];
    const float* fc_W    = (const float*)d_in[19];
    const float* fc_b    = (const float*)d_in[20];

    char* ws = (char*)d_ws;
    size_t o = 0;
    bf16*   feats   = (bf16*)(ws + o);   o += (size_t)2048 * 1024 * 2;
    float*  Wf      = (float*)(ws + o);  o += (size_t)2048 * 512 * 4;
    float*  Uo      = (float*)(ws + o);  o += (size_t)1152 * 512 * 4;
    float*  gatesF  = (float*)(ws + o);  o += (size_t)2097152 * 4;
    float*  gatesB  = (float*)(ws + o);  o += (size_t)2097152 * 4;
    uint32* hx      = (uint32*)(ws + o); o += (size_t)2 * 16384 * 4;
    int*    bar     = (int*)(ws + o);    o += 256;
    bf16*  visual_b  = (bf16*)(ws + o); o += (size_t)4194304 * 2;
    bf16*  objects_b = (bf16*)(ws + o); o += (size_t)589824 * 2;
    bf16*  lin_Wb    = (bf16*)(ws + o); o += (size_t)1048576 * 2;
    bf16*  W_Wb      = (bf16*)(ws + o); o += (size_t)262144 * 2;
    bf16*  U_Wb      = (bf16*)(ws + o); o += (size_t)262144 * 2;
    bf16*  Wih_fb    = (bf16*)(ws + o); o += (size_t)1048576 * 2;
    bf16*  Whh_fb    = (bf16*)(ws + o); o += (size_t)262144 * 2;
    bf16*  Wih_bb    = (bf16*)(ws + o); o += (size_t)1048576 * 2;
    bf16*  Whh_bb    = (bf16*)(ws + o); o += (size_t)262144 * 2;

    hipMemsetAsync(bar, 0, 256, stream);

    CvtJobs cj;
    const float* srcs[9] = {visual, objects, lin_W, W_W, U_W, Wih_f, Whh_f, Wih_b, Whh_b};
    bf16* dsts[9] = {visual_b, objects_b, lin_Wb, W_Wb, U_Wb, Wih_fb, Whh_fb, Wih_bb, Whh_bb};
    int ns[9] = {4194304, 589824, 1048576, 262144, 262144, 1048576, 262144, 1048576, 262144};
    int acc_b = 0;
    for (int i = 0; i < 9; ++i) {
        cj.src[i] = srcs[i];
        cj.dst[i] = dsts[i];
        cj.start[i] = acc_b;
        acc_b += ns[i] / 1024;
    }
    cj.start[9] = acc_b;

    dim3 blk(256);
    cvt_kernel<<<acc_b, blk, 0, stream>>>(cj);

    // f3d (128 blocks) + Uo (72 blocks)
    gemm_pre<<<200, blk, 0, stream>>>(visual_b, lin_Wb, lin_b,
                                      objects_b, U_Wb, U_b, b_attn, feats, Uo);
    // Wf = f3d@W_W^T + W_b
    gemm_wf<<<128, blk, 0, stream>>>(feats, W_Wb, W_b, Wf);
    // fused attention -> feats[:, 512:]  (LDS-staged Uo)
    attn_kernel<<<256, blk, 0, stream>>>(Wf, Uo, w_W, w_b, feats);
    // gate projections, both dirs, f32 out [64][32][1024]
    gemm_gates<<<256, blk, 0, stream>>>(feats, Wih_fb, Wih_bb,
                                        bih_f, bhh_f, bih_b, bhh_b,
                                        gatesF, gatesB);
    // recurrent BiLSTM -> d_out[0 .. 1048575]
    lstm_kernel<<<8, blk, 0, stream>>>(Whh_fb, Whh_bb, gatesF, gatesB, hx,
                                       (float*)d_out, bar);
    // action max + fc -> d_out[1048576 ..]
    final_kernel<<<32, blk, 0, stream>>>((float*)d_out, fc_W, fc_b,
                                         (float*)d_out + 1048576);
}